// Round 2
// baseline (16208.331 us; speedup 1.0000x reference)
//
#include <hip/hip_runtime.h>

constexpr int BB = 32;
constexpr int TT = 512;
constexpr size_t MSZ = (size_t)BB * TT * 128;             // one embedding array (floats)
constexpr size_t M_OFF = 0;                               // 3 * MSZ
constexpr size_t MASK_OFF = 3 * MSZ;                      // 3*B*T ints
constexpr size_t SUM_OFF = MASK_OFF + (size_t)3 * BB * TT;    // 4 * MSZ
constexpr size_t WHH_OFF = SUM_OFF + 4 * MSZ;             // 256*1024 floats [k][hid][gate]
constexpr size_t WIH_OFF = WHH_OFF + (size_t)256 * 1024;  // 256*1024 floats [k][hid][gate]
constexpr size_t BIAS_OFF = WIH_OFF + (size_t)256 * 1024; // 1024 floats [hid][gate]
constexpr size_t FSEL_OFF = BIAS_OFF + 1024;              // 128*256 floats
constexpr size_t XG_OFF = FSEL_OFF + (size_t)128 * 256;   // 128*512*1024 floats (precomputed x-gates)
constexpr size_t TOTAL_FLOATS = XG_OFF + (size_t)128 * 512 * 1024;
constexpr size_t FULL_BYTES = TOTAL_FLOATS * 4;

__device__ __forceinline__ float sigm(float x) {
  return __builtin_amdgcn_rcpf(1.f + __builtin_amdgcn_exp2f(-1.44269504f * x));
}
__device__ __forceinline__ float tanhfast(float x) {
  float e = __builtin_amdgcn_exp2f(2.88539008f * x);
  return 1.f - 2.f * __builtin_amdgcn_rcpf(e + 1.f);
}
__device__ __forceinline__ float leaky(float x) { return x >= 0.f ? x : 0.1f * x; }

// m = leaky(xy @ W_mlp^T + b_mlp), one thread per output element
__global__ __launch_bounds__(256) void embed_kernel(
    const float* __restrict__ a, const float* __restrict__ t,
    const float* __restrict__ n, const float* __restrict__ Wm,
    const float* __restrict__ bm, float* __restrict__ ws) {
  int idx = blockIdx.x * 256 + threadIdx.x;   // < 3*B*T*128
  int h = idx & 127;
  int bt = idx >> 7;
  int traj = bt / (BB * TT);
  int r = bt - traj * (BB * TT);
  const float* src = traj == 0 ? a : (traj == 1 ? t : n);
  float x0 = src[r * 4 + 0], x1 = src[r * 4 + 1];
  float v = x0 * Wm[2 * h] + x1 * Wm[2 * h + 1] + bm[h];
  ws[M_OFF + (size_t)traj * MSZ + (size_t)r * 128 + h] = leaky(v);
}

// grid-id mask
__global__ __launch_bounds__(256) void mask_kernel(
    const float* __restrict__ a, const float* __restrict__ t,
    const float* __restrict__ n, float* __restrict__ ws) {
  int idx = blockIdx.x * 256 + threadIdx.x;   // < 3*B*T
  int traj = idx / (BB * TT);
  int r = idx - traj * (BB * TT);
  const float* src = traj == 0 ? a : (traj == 1 ? t : n);
  float gx = src[r * 4 + 2], gy = src[r * 4 + 3];
  ((int*)(ws + MASK_OFF))[idx] = (gy * 128.f + gx - 257.f) >= 0.5f ? 1 : 0;
}

// transpose Whh and Wih to [k][hid][gate] (torch gate order i,f,g,o); fold biases
__global__ __launch_bounds__(256) void wt_kernel(
    const float* __restrict__ Wih, const float* __restrict__ Whh,
    const float* __restrict__ bih, const float* __restrict__ bhh,
    float* __restrict__ ws) {
  int idx = blockIdx.x * 256 + threadIdx.x;  // < 525312
  if (idx < 262144) {
    int k = idx >> 10;
    int rest = idx & 1023;
    int hid = rest >> 2, g = rest & 3;
    ws[WHH_OFF + idx] = Whh[(g * 256 + hid) * 256 + k];
  } else if (idx < 524288) {
    int j = idx - 262144;
    int k = j >> 10;
    int rest = j & 1023;
    int hid = rest >> 2, g = rest & 3;
    ws[WIH_OFF + j] = Wih[(g * 256 + hid) * 256 + k];
  } else if (idx < 525312) {
    int j = idx - 524288;
    int hid = j >> 2, g = j & 3;
    ws[BIAS_OFF + j] = bih[g * 256 + hid] + bhh[g * 256 + hid];
  }
}

// one WG per (job, batch, 16-row t-tile); job 0..3 = L0..L3 source/dest pairs
__global__ __launch_bounds__(256) void attn_kernel(float* __restrict__ ws) {
  __shared__ float srcL[16][129];
  __shared__ float dtile[128][34];     // transposed dst tile [k][s], S_TILE=32
  __shared__ float scoresL[16][514];
  __shared__ float rowscaleL[16];
  __shared__ int maskD[32];
  __shared__ int maskS[16];

  int tid = threadIdx.x;
  int job = blockIdx.x >> 10;
  int rem = blockIdx.x & 1023;
  int b = rem >> 5, ttile = rem & 31;
  int t0 = ttile * 16;
  int srcTr = (job == 1) ? 1 : ((job == 3) ? 2 : 0);
  int dstTr = (job == 0) ? 1 : ((job == 2) ? 2 : 0);
  const float* msrc = ws + M_OFF + (size_t)srcTr * MSZ + (size_t)b * TT * 128;
  const float* mdst = ws + M_OFF + (size_t)dstTr * MSZ + (size_t)b * TT * 128;
  const int* maskbase = (const int*)(ws + MASK_OFF);
  const int* smask = maskbase + srcTr * BB * TT + b * TT;
  const int* dmask = maskbase + dstTr * BB * TT + b * TT;
  float* out = ws + SUM_OFF + (size_t)job * MSZ + (size_t)b * TT * 128;

  for (int i = 0; i < 8; i++) {
    int idx = i * 256 + tid;
    int tr = idx >> 7, k = idx & 127;
    srcL[tr][k] = msrc[(size_t)(t0 + tr) * 128 + k];
  }
  if (tid < 16) maskS[tid] = smask[t0 + tid];
  __syncthreads();

  // pass 1: scores (invalid dst -> -1e9, exact ref semantics)
  int s2 = tid & 15, trr = tid >> 4;
  for (int st = 0; st < 16; st++) {
    int s0 = st * 32;
    for (int i = 0; i < 16; i++) {
      int idx = i * 256 + tid;
      int s = idx >> 7, k = idx & 127;
      dtile[k][s] = mdst[(size_t)(s0 + s) * 128 + k];
    }
    if (tid < 32) maskD[tid] = dmask[s0 + tid];
    __syncthreads();
    float d0 = 0.f, d1 = 0.f;
#pragma unroll 8
    for (int k = 0; k < 128; k++) {
      float sv = srcL[trr][k];
      float2 dv = *(const float2*)&dtile[k][2 * s2];
      d0 += sv * dv.x;
      d1 += sv * dv.y;
    }
    scoresL[trr][s0 + 2 * s2]     = maskD[2 * s2]     ? d0 : -1e9f;
    scoresL[trr][s0 + 2 * s2 + 1] = maskD[2 * s2 + 1] ? d1 : -1e9f;
    __syncthreads();
  }

  // softmax per row
  {
    int r = tid >> 4, j = tid & 15;  // 16 threads per row, same wave
    float mx = -3.0e38f;
    for (int i = 0; i < 32; i++) mx = fmaxf(mx, scoresL[r][j + 16 * i]);
    for (int m = 1; m < 16; m <<= 1) mx = fmaxf(mx, __shfl_xor(mx, m, 64));
    float den = 0.f;
    for (int i = 0; i < 32; i++) {
      float p = __builtin_amdgcn_exp2f((scoresL[r][j + 16 * i] - mx) * 1.44269504f);
      scoresL[r][j + 16 * i] = p;
      den += p;
    }
    for (int m = 1; m < 16; m <<= 1) den += __shfl_xor(den, m, 64);
    if (j == 0) rowscaleL[r] = (maskS[r] && mx > -5e8f) ? (1.f / den) : 0.f;
  }
  __syncthreads();

  // pass 2: weighted sum over dst
  int kk = tid & 127, tix = tid >> 7;
  float acc[8];
#pragma unroll
  for (int u = 0; u < 8; u++) acc[u] = 0.f;
  for (int st = 0; st < 16; st++) {
    int s0 = st * 32;
    for (int i = 0; i < 16; i++) {
      int idx = i * 256 + tid;
      int s = idx >> 7, k = idx & 127;
      dtile[k][s] = mdst[(size_t)(s0 + s) * 128 + k];
    }
    __syncthreads();
    for (int s = 0; s < 32; s += 2) {
      float2 dv = *(const float2*)&dtile[kk][s];
#pragma unroll
      for (int u = 0; u < 8; u++) {
        float2 p = *(const float2*)&scoresL[tix * 8 + u][s0 + s];
        acc[u] += p.x * dv.x + p.y * dv.y;
      }
    }
    __syncthreads();
  }
#pragma unroll
  for (int u = 0; u < 8; u++) {
    int tr = tix * 8 + u;
    out[(size_t)(t0 + tr) * 128 + kk] = acc[u] * rowscaleL[tr];
  }
}

// xg[seq][t][hid*4+gate] = xcat @ WihT + bias  (M=65536, K=256, N=1024)
// tile 64 rows(t) x 256 cols; 256 threads, each 8x8 sub-block
__global__ __launch_bounds__(256) void xg_kernel(float* __restrict__ ws) {
  __shared__ float aT[32][68];    // [kk][m], padded for write conflicts + f4 alignment
  __shared__ float bL[32][256];   // [kk][n]
  int tid = threadIdx.x;
  int bx = blockIdx.x;            // 128*8*4 = 4096
  int seq = bx >> 5;
  int tt = (bx >> 2) & 7;
  int nc = bx & 3;
  int t0 = tt * 64;
  int l = seq >> 5, b = seq & 31;
  int srcTr = (l == 1) ? 1 : ((l == 3) ? 2 : 0);
  const float* xrow = ws + M_OFF + (size_t)srcTr * MSZ + (size_t)b * TT * 128;
  const float* srow = ws + SUM_OFF + (size_t)l * MSZ + (size_t)b * TT * 128;

  int r0 = tid >> 5;              // 0..7 (row group of 8)
  int c0 = (tid & 31) * 8;        // col within 256-tile

  float acc[8][8];
#pragma unroll
  for (int i = 0; i < 8; i++)
#pragma unroll
    for (int j = 0; j < 8; j++) acc[i][j] = 0.f;

  for (int kc = 0; kc < 8; kc++) {
    int kbase = kc * 32;
    __syncthreads();
    // stage A: 64 t x 32 k
#pragma unroll
    for (int i = 0; i < 8; i++) {
      int idx = i * 256 + tid;
      int m = idx >> 5, kk = idx & 31;
      float v;
      if (kbase < 128) {
        v = xrow[(size_t)(t0 + m) * 128 + kbase + kk];
      } else {
        int k2 = kbase + kk - 128;
        v = xrow[(size_t)(t0 + m) * 128 + k2] - srow[(size_t)(t0 + m) * 128 + k2];
      }
      aT[kk][m] = v;
    }
    // stage B: 32 k x 256 n
#pragma unroll
    for (int i = 0; i < 32; i++) {
      int idx = i * 256 + tid;
      int kk = idx >> 8, n = idx & 255;
      bL[kk][n] = ws[WIH_OFF + (size_t)(kbase + kk) * 1024 + nc * 256 + n];
    }
    __syncthreads();
#pragma unroll 2
    for (int kk = 0; kk < 32; kk++) {
      float4 a0 = *(const float4*)&aT[kk][r0 * 8];
      float4 a1 = *(const float4*)&aT[kk][r0 * 8 + 4];
      float4 b0 = *(const float4*)&bL[kk][c0];
      float4 b1 = *(const float4*)&bL[kk][c0 + 4];
      float av[8] = {a0.x, a0.y, a0.z, a0.w, a1.x, a1.y, a1.z, a1.w};
      float bv[8] = {b0.x, b0.y, b0.z, b0.w, b1.x, b1.y, b1.z, b1.w};
#pragma unroll
      for (int i = 0; i < 8; i++)
#pragma unroll
        for (int j = 0; j < 8; j++) acc[i][j] += av[i] * bv[j];
    }
  }

  float4 bias0 = *(const float4*)&ws[BIAS_OFF + nc * 256 + c0];
  float4 bias1 = *(const float4*)&ws[BIAS_OFF + nc * 256 + c0 + 4];
#pragma unroll
  for (int i = 0; i < 8; i++) {
    int t = t0 + r0 * 8 + i;
    float* o = ws + XG_OFF + ((size_t)seq * TT + t) * 1024 + nc * 256 + c0;
    float4 v0 = {acc[i][0] + bias0.x, acc[i][1] + bias0.y,
                 acc[i][2] + bias0.z, acc[i][3] + bias0.w};
    float4 v1 = {acc[i][4] + bias1.x, acc[i][5] + bias1.y,
                 acc[i][6] + bias1.z, acc[i][7] + bias1.w};
    *(float4*)o = v0;
    *(float4*)(o + 4) = v1;
  }
}

// recurrence: 64 WGs x 512 threads; WG owns 2 sequences.
// USE_XG: gates start from precomputed xg (K=256 recurrent only).
// else:   also accumulate x-part from WihT each step (K=512 total).
template <bool USE_XG>
__global__ __launch_bounds__(512, 2) void rec_kernel(
    float* __restrict__ ws, const int* __restrict__ la,
    const int* __restrict__ lt, const int* __restrict__ ln) {
  __shared__ float hL[2][256];
  __shared__ float xL[2][256];
  int tid = threadIdx.x;
  int sl = tid >> 8;
  int hid = tid & 255;
  int seq = blockIdx.x * 2 + sl;
  int l = seq >> 5, b = seq & 31;
  int srcTr = (l == 1) ? 1 : ((l == 3) ? 2 : 0);
  const float* xrow = ws + M_OFF + (size_t)srcTr * MSZ + (size_t)b * TT * 128;
  const float* srow = ws + SUM_OFF + (size_t)l * MSZ + (size_t)b * TT * 128;
  const int* lens = (l == 1) ? lt : ((l == 3) ? ln : la);
  int mylen = lens[b];
  const float* wh = ws + WHH_OFF + (hid << 2);
  const float* wi = ws + WIH_OFF + (hid << 2);
  const float* xgrow = ws + XG_OFF + (size_t)seq * TT * 1024 + (hid << 2);
  float4 biasv;
  if (!USE_XG) biasv = *(const float4*)&ws[BIAS_OFF + (hid << 2)];
  float c = 0.f;
  hL[sl][hid] = 0.f;
  if (!USE_XG) {
    xL[sl][hid] = hid < 128 ? xrow[hid] : xrow[hid - 128] - srow[hid - 128];
  }
  __syncthreads();
  float* fout = ws + FSEL_OFF + (size_t)seq * 256;

  for (int t = 0; t < TT; t++) {
    float gi, gf, gg, go;
    if (USE_XG) {
      float4 g4 = *(const float4*)(xgrow + (size_t)t * 1024);
      gi = g4.x; gf = g4.y; gg = g4.z; go = g4.w;
    } else {
      gi = biasv.x; gf = biasv.y; gg = biasv.z; go = biasv.w;
    }
    // h part: K=256
    {
      const float* hp = &hL[sl][0];
#pragma unroll 4
      for (int k = 0; k < 256; k += 4) {
        float4 hv = *(const float4*)(hp + k);
        const float* w = wh + (size_t)k * 1024;
        float4 w0 = *(const float4*)(w);
        float4 w1 = *(const float4*)(w + 1024);
        float4 w2 = *(const float4*)(w + 2048);
        float4 w3 = *(const float4*)(w + 3072);
        gi += hv.x * w0.x + hv.y * w1.x + hv.z * w2.x + hv.w * w3.x;
        gf += hv.x * w0.y + hv.y * w1.y + hv.z * w2.y + hv.w * w3.y;
        gg += hv.x * w0.z + hv.y * w1.z + hv.z * w2.z + hv.w * w3.z;
        go += hv.x * w0.w + hv.y * w1.w + hv.z * w2.w + hv.w * w3.w;
      }
    }
    if (!USE_XG) {
      const float* xp = &xL[sl][0];
#pragma unroll 4
      for (int k = 0; k < 256; k += 4) {
        float4 xv = *(const float4*)(xp + k);
        const float* w = wi + (size_t)k * 1024;
        float4 w0 = *(const float4*)(w);
        float4 w1 = *(const float4*)(w + 1024);
        float4 w2 = *(const float4*)(w + 2048);
        float4 w3 = *(const float4*)(w + 3072);
        gi += xv.x * w0.x + xv.y * w1.x + xv.z * w2.x + xv.w * w3.x;
        gf += xv.x * w0.y + xv.y * w1.y + xv.z * w2.y + xv.w * w3.y;
        gg += xv.x * w0.z + xv.y * w1.z + xv.z * w2.z + xv.w * w3.z;
        go += xv.x * w0.w + xv.y * w1.w + xv.z * w2.w + xv.w * w3.w;
      }
    }
    float c_new = sigm(gf) * c + sigm(gi) * tanhfast(gg);
    c = c_new;
    float h = sigm(go) * tanhfast(c_new);
    __syncthreads();                 // all reads of hL/xL done
    hL[sl][hid] = h;
    if (!USE_XG && t + 1 < TT) {
      int tn = t + 1;
      xL[sl][hid] = hid < 128 ? xrow[tn * 128 + hid]
                              : xrow[tn * 128 + hid - 128] - srow[tn * 128 + hid - 128];
    }
    if (t == mylen - 1) fout[hid] = h;
    __syncthreads();                 // writes visible
  }
}

// gate head on a-side + pairwise distance + exp
__global__ __launch_bounds__(256) void finish_kernel(
    const float* __restrict__ ws, const float* __restrict__ W1,
    const float* __restrict__ b1, const float* __restrict__ W2,
    const float* __restrict__ b2, const float* __restrict__ W3,
    const float* __restrict__ b3, float* __restrict__ out) {
  __shared__ float oL[256];
  __shared__ float wsum[4];
  int tid = threadIdx.x;
  int p = blockIdx.x >> 5, b = blockIdx.x & 31;
  const float* fa = ws + FSEL_OFF + (size_t)((2 * p) * 32 + b) * 256;
  const float* fb = ws + FSEL_OFF + (size_t)((2 * p + 1) * 32 + b) * 256;
  oL[tid] = fa[tid];
  __syncthreads();
  float a1 = b1[tid], a2 = b2[tid], a3 = b3[tid];
  const float* w1r = W1 + tid * 256;
  const float* w2r = W2 + tid * 256;
  const float* w3r = W3 + tid * 256;
  for (int k = 0; k < 256; k++) {
    float ov = oL[k];
    a1 += ov * w1r[k];
    a2 += ov * w2r[k];
    a3 += ov * w3r[k];
  }
  float cg = sigm(a1) * leaky(a2);
  float res = oL[tid] + sigm(a3) * leaky(cg);
  float d = res - fb[tid] + 1e-6f;
  float sq = d * d;
  for (int m = 32; m >= 1; m >>= 1) sq += __shfl_down(sq, m, 64);
  if ((tid & 63) == 0) wsum[tid >> 6] = sq;
  __syncthreads();
  if (tid == 0) {
    float s = wsum[0] + wsum[1] + wsum[2] + wsum[3];
    out[p * BB + b] = expf(sqrtf(s));
  }
}

extern "C" void kernel_launch(void* const* d_in, const int* in_sizes, int n_in,
                              void* d_out, int out_size, void* d_ws, size_t ws_size,
                              hipStream_t stream) {
  const float* anchor = (const float*)d_in[0];
  const float* trajs = (const float*)d_in[1];
  const float* negat = (const float*)d_in[2];
  const int* la = (const int*)d_in[3];
  const int* lt = (const int*)d_in[4];
  const int* ln = (const int*)d_in[5];
  const float* Wm = (const float*)d_in[6];
  const float* bm = (const float*)d_in[7];
  const float* Wih = (const float*)d_in[8];
  const float* Whh = (const float*)d_in[9];
  const float* bih = (const float*)d_in[10];
  const float* bhh = (const float*)d_in[11];
  const float* W1 = (const float*)d_in[12];
  const float* b1 = (const float*)d_in[13];
  const float* W2 = (const float*)d_in[14];
  const float* b2 = (const float*)d_in[15];
  const float* W3 = (const float*)d_in[16];
  const float* b3 = (const float*)d_in[17];
  float* ws = (float*)d_ws;
  float* out = (float*)d_out;

  bool full = ws_size >= FULL_BYTES;

  embed_kernel<<<(3 * BB * TT * 128) / 256, 256, 0, stream>>>(anchor, trajs, negat, Wm, bm, ws);
  mask_kernel<<<(3 * BB * TT) / 256, 256, 0, stream>>>(anchor, trajs, negat, ws);
  wt_kernel<<<2052, 256, 0, stream>>>(Wih, Whh, bih, bhh, ws);
  attn_kernel<<<4096, 256, 0, stream>>>(ws);
  if (full) {
    xg_kernel<<<4096, 256, 0, stream>>>(ws);
    rec_kernel<true><<<64, 512, 0, stream>>>(ws, la, lt, ln);
  } else {
    rec_kernel<false><<<64, 512, 0, stream>>>(ws, la, lt, ln);
  }
  finish_kernel<<<64, 256, 0, stream>>>(ws, W1, b1, W2, b2, W3, b3, out);
}

// Round 3
// 8859.727 us; speedup vs baseline: 1.8294x; 1.8294x over previous
//
#include <hip/hip_runtime.h>

constexpr int BB = 32;
constexpr int TT = 512;
constexpr size_t MSZ = (size_t)BB * TT * 128;              // one embedding array (floats)
constexpr size_t M_OFF = 0;                                // 3 * MSZ
constexpr size_t MASK_OFF = 3 * MSZ;                       // 3*B*T ints
constexpr size_t SUM_OFF = MASK_OFF + (size_t)3 * BB * TT; // 4 * MSZ
constexpr size_t WHH_OFF = SUM_OFF + 4 * MSZ;              // 256*1024 floats [k][hid][gate]
constexpr size_t WIH_OFF = WHH_OFF + (size_t)256 * 1024;   // 256*1024 floats [k][hid][gate]
constexpr size_t BIAS_OFF = WIH_OFF + (size_t)256 * 1024;  // 1024 floats [hid][gate]
constexpr size_t FSEL_OFF = BIAS_OFF + 1024;               // 128*256 floats
constexpr size_t STATE_OFF = FSEL_OFF + (size_t)128 * 256; // h(32768) + c(32768)
constexpr size_t XGBUF_OFF = STATE_OFF + 65536;            // CH*128*1024 floats (chunked x-gates)

__device__ __forceinline__ float sigm(float x) {
  return __builtin_amdgcn_rcpf(1.f + __builtin_amdgcn_exp2f(-1.44269504f * x));
}
__device__ __forceinline__ float tanhfast(float x) {
  float e = __builtin_amdgcn_exp2f(2.88539008f * x);
  return 1.f - 2.f * __builtin_amdgcn_rcpf(e + 1.f);
}
__device__ __forceinline__ float leaky(float x) { return x >= 0.f ? x : 0.1f * x; }

__global__ __launch_bounds__(256) void embed_kernel(
    const float* __restrict__ a, const float* __restrict__ t,
    const float* __restrict__ n, const float* __restrict__ Wm,
    const float* __restrict__ bm, float* __restrict__ ws) {
  int idx = blockIdx.x * 256 + threadIdx.x;   // < 3*B*T*128
  int h = idx & 127;
  int bt = idx >> 7;
  int traj = bt / (BB * TT);
  int r = bt - traj * (BB * TT);
  const float* src = traj == 0 ? a : (traj == 1 ? t : n);
  float x0 = src[r * 4 + 0], x1 = src[r * 4 + 1];
  float v = x0 * Wm[2 * h] + x1 * Wm[2 * h + 1] + bm[h];
  ws[M_OFF + (size_t)traj * MSZ + (size_t)r * 128 + h] = leaky(v);
}

__global__ __launch_bounds__(256) void mask_kernel(
    const float* __restrict__ a, const float* __restrict__ t,
    const float* __restrict__ n, float* __restrict__ ws) {
  int idx = blockIdx.x * 256 + threadIdx.x;   // < 3*B*T
  int traj = idx / (BB * TT);
  int r = idx - traj * (BB * TT);
  const float* src = traj == 0 ? a : (traj == 1 ? t : n);
  float gx = src[r * 4 + 2], gy = src[r * 4 + 3];
  ((int*)(ws + MASK_OFF))[idx] = (gy * 128.f + gx - 257.f) >= 0.5f ? 1 : 0;
}

// transpose Whh and Wih to [k][hid][gate] (torch gate order i,f,g,o); fold biases
__global__ __launch_bounds__(256) void wt_kernel(
    const float* __restrict__ Wih, const float* __restrict__ Whh,
    const float* __restrict__ bih, const float* __restrict__ bhh,
    float* __restrict__ ws) {
  int idx = blockIdx.x * 256 + threadIdx.x;  // < 525312
  if (idx < 262144) {
    int k = idx >> 10;
    int rest = idx & 1023;
    int hid = rest >> 2, g = rest & 3;
    ws[WHH_OFF + idx] = Whh[(g * 256 + hid) * 256 + k];
  } else if (idx < 524288) {
    int j = idx - 262144;
    int k = j >> 10;
    int rest = j & 1023;
    int hid = rest >> 2, g = rest & 3;
    ws[WIH_OFF + j] = Wih[(g * 256 + hid) * 256 + k];
  } else if (idx < 525312) {
    int j = idx - 524288;
    int hid = j >> 2, g = j & 3;
    ws[BIAS_OFF + j] = bih[g * 256 + hid] + bhh[g * 256 + hid];
  }
}

// one WG per (job, batch, 16-row t-tile); job 0..3 = L0..L3 source/dest pairs
__global__ __launch_bounds__(256) void attn_kernel(float* __restrict__ ws) {
  __shared__ float srcL[16][129];
  __shared__ float dtile[128][34];
  __shared__ float scoresL[16][514];
  __shared__ float rowscaleL[16];
  __shared__ int maskD[32];
  __shared__ int maskS[16];

  int tid = threadIdx.x;
  int job = blockIdx.x >> 10;
  int rem = blockIdx.x & 1023;
  int b = rem >> 5, ttile = rem & 31;
  int t0 = ttile * 16;
  int srcTr = (job == 1) ? 1 : ((job == 3) ? 2 : 0);
  int dstTr = (job == 0) ? 1 : ((job == 2) ? 2 : 0);
  const float* msrc = ws + M_OFF + (size_t)srcTr * MSZ + (size_t)b * TT * 128;
  const float* mdst = ws + M_OFF + (size_t)dstTr * MSZ + (size_t)b * TT * 128;
  const int* maskbase = (const int*)(ws + MASK_OFF);
  const int* smask = maskbase + srcTr * BB * TT + b * TT;
  const int* dmask = maskbase + dstTr * BB * TT + b * TT;
  float* out = ws + SUM_OFF + (size_t)job * MSZ + (size_t)b * TT * 128;

  for (int i = 0; i < 8; i++) {
    int idx = i * 256 + tid;
    int tr = idx >> 7, k = idx & 127;
    srcL[tr][k] = msrc[(size_t)(t0 + tr) * 128 + k];
  }
  if (tid < 16) maskS[tid] = smask[t0 + tid];
  __syncthreads();

  int s2 = tid & 15, trr = tid >> 4;
  for (int st = 0; st < 16; st++) {
    int s0 = st * 32;
    for (int i = 0; i < 16; i++) {
      int idx = i * 256 + tid;
      int s = idx >> 7, k = idx & 127;
      dtile[k][s] = mdst[(size_t)(s0 + s) * 128 + k];
    }
    if (tid < 32) maskD[tid] = dmask[s0 + tid];
    __syncthreads();
    float d0 = 0.f, d1 = 0.f;
#pragma unroll 8
    for (int k = 0; k < 128; k++) {
      float sv = srcL[trr][k];
      float2 dv = *(const float2*)&dtile[k][2 * s2];
      d0 += sv * dv.x;
      d1 += sv * dv.y;
    }
    scoresL[trr][s0 + 2 * s2]     = maskD[2 * s2]     ? d0 : -1e9f;
    scoresL[trr][s0 + 2 * s2 + 1] = maskD[2 * s2 + 1] ? d1 : -1e9f;
    __syncthreads();
  }

  {
    int r = tid >> 4, j = tid & 15;
    float mx = -3.0e38f;
    for (int i = 0; i < 32; i++) mx = fmaxf(mx, scoresL[r][j + 16 * i]);
    for (int m = 1; m < 16; m <<= 1) mx = fmaxf(mx, __shfl_xor(mx, m, 64));
    float den = 0.f;
    for (int i = 0; i < 32; i++) {
      float p = __builtin_amdgcn_exp2f((scoresL[r][j + 16 * i] - mx) * 1.44269504f);
      scoresL[r][j + 16 * i] = p;
      den += p;
    }
    for (int m = 1; m < 16; m <<= 1) den += __shfl_xor(den, m, 64);
    if (j == 0) rowscaleL[r] = (maskS[r] && mx > -5e8f) ? (1.f / den) : 0.f;
  }
  __syncthreads();

  int kk = tid & 127, tix = tid >> 7;
  float acc[8];
#pragma unroll
  for (int u = 0; u < 8; u++) acc[u] = 0.f;
  for (int st = 0; st < 16; st++) {
    int s0 = st * 32;
    for (int i = 0; i < 16; i++) {
      int idx = i * 256 + tid;
      int s = idx >> 7, k = idx & 127;
      dtile[k][s] = mdst[(size_t)(s0 + s) * 128 + k];
    }
    __syncthreads();
    for (int s = 0; s < 32; s += 2) {
      float2 dv = *(const float2*)&dtile[kk][s];
#pragma unroll
      for (int u = 0; u < 8; u++) {
        float2 p = *(const float2*)&scoresL[tix * 8 + u][s0 + s];
        acc[u] += p.x * dv.x + p.y * dv.y;
      }
    }
    __syncthreads();
  }
#pragma unroll
  for (int u = 0; u < 8; u++) {
    int tr = tix * 8 + u;
    out[(size_t)(t0 + tr) * 128 + kk] = acc[u] * rowscaleL[tr];
  }
}

// chunked x-gate GEMM: xg[seq][t-tc0][1024] = xcat @ WihT + bias for t in [tc0, tc0+CH)
__global__ __launch_bounds__(256) void xg_kernel(
    float* __restrict__ ws, int tc0, int CH,
    const int* __restrict__ la, const int* __restrict__ lt, const int* __restrict__ ln) {
  __shared__ float aT[32][68];
  __shared__ float bL[32][256];
  int tid = threadIdx.x;
  int bx = blockIdx.x;
  int tt4 = (CH >> 6) << 2;       // tiles*4 per seq
  int seq = bx / tt4;
  int rem = bx - seq * tt4;
  int tt = rem >> 2;
  int nc = rem & 3;
  int t0 = tc0 + tt * 64;
  int l = seq >> 5, b = seq & 31;
  const int* lens = (l == 1) ? lt : ((l == 3) ? ln : la);
  if (t0 >= lens[b]) return;      // beyond this sequence's length: dead work
  int srcTr = (l == 1) ? 1 : ((l == 3) ? 2 : 0);
  const float* xrow = ws + M_OFF + (size_t)srcTr * MSZ + (size_t)b * TT * 128;
  const float* srow = ws + SUM_OFF + (size_t)l * MSZ + (size_t)b * TT * 128;

  int r0 = tid >> 5;
  int c0 = (tid & 31) * 8;

  float acc[8][8];
#pragma unroll
  for (int i = 0; i < 8; i++)
#pragma unroll
    for (int j = 0; j < 8; j++) acc[i][j] = 0.f;

  for (int kc = 0; kc < 8; kc++) {
    int kbase = kc * 32;
    __syncthreads();
#pragma unroll
    for (int i = 0; i < 8; i++) {
      int idx = i * 256 + tid;
      int m = idx >> 5, kk = idx & 31;
      float v;
      if (kbase < 128) {
        v = xrow[(size_t)(t0 + m) * 128 + kbase + kk];
      } else {
        int k2 = kbase + kk - 128;
        v = xrow[(size_t)(t0 + m) * 128 + k2] - srow[(size_t)(t0 + m) * 128 + k2];
      }
      aT[kk][m] = v;
    }
#pragma unroll
    for (int i = 0; i < 32; i++) {
      int idx = i * 256 + tid;
      int kk = idx >> 8, n = idx & 255;
      bL[kk][n] = ws[WIH_OFF + (size_t)(kbase + kk) * 1024 + nc * 256 + n];
    }
    __syncthreads();
#pragma unroll 2
    for (int kk = 0; kk < 32; kk++) {
      float4 a0 = *(const float4*)&aT[kk][r0 * 8];
      float4 a1 = *(const float4*)&aT[kk][r0 * 8 + 4];
      float4 b0 = *(const float4*)&bL[kk][c0];
      float4 b1 = *(const float4*)&bL[kk][c0 + 4];
      float av[8] = {a0.x, a0.y, a0.z, a0.w, a1.x, a1.y, a1.z, a1.w};
      float bv[8] = {b0.x, b0.y, b0.z, b0.w, b1.x, b1.y, b1.z, b1.w};
#pragma unroll
      for (int i = 0; i < 8; i++)
#pragma unroll
        for (int j = 0; j < 8; j++) acc[i][j] += av[i] * bv[j];
    }
  }

  float4 bias0 = *(const float4*)&ws[BIAS_OFF + nc * 256 + c0];
  float4 bias1 = *(const float4*)&ws[BIAS_OFF + nc * 256 + c0 + 4];
#pragma unroll
  for (int i = 0; i < 8; i++) {
    int tl = t0 - tc0 + r0 * 8 + i;
    float* o = ws + XGBUF_OFF + ((size_t)seq * CH + tl) * 1024 + nc * 256 + c0;
    float4 v0 = {acc[i][0] + bias0.x, acc[i][1] + bias0.y,
                 acc[i][2] + bias0.z, acc[i][3] + bias0.w};
    float4 v1 = {acc[i][4] + bias1.x, acc[i][5] + bias1.y,
                 acc[i][6] + bias1.z, acc[i][7] + bias1.w};
    *(float4*)o = v0;
    *(float4*)(o + 4) = v1;
  }
}

// recurrence over one chunk: 64 WGs x 512 threads, 2 seqs/WG.
// thread: hid = tid>>1, ks = tid&1 (K-half). Lane-pair shuffle reduction.
// h ping-pong in LDS; c in registers; state carried in ws across chunks.
__global__ __launch_bounds__(512, 2) void rec2_kernel(
    float* __restrict__ ws, const int* __restrict__ la,
    const int* __restrict__ lt, const int* __restrict__ ln,
    int t0c, int CH) {
  __shared__ float hbuf[2][2][256];
  int tid = threadIdx.x;
  int hid = tid >> 1;
  int ks = tid & 1;
  int s0 = blockIdx.x * 2;
  int l = s0 >> 5;                 // pair never straddles an l-group
  int b0 = s0 & 31, b1 = b0 + 1;
  const int* lens = (l == 1) ? lt : ((l == 3) ? ln : la);
  int lenA = lens[b0], lenB = lens[b1];
  int tend = min(CH, max(lenA, lenB) - t0c);
  if (tend <= 0) return;

  float* sh = ws + STATE_OFF;              // h state [128][256]
  float* sc = ws + STATE_OFF + 32768;      // c state [128][256]
  float cA, cB, hA, hB;
  if (t0c == 0) {
    cA = 0.f; cB = 0.f; hA = 0.f; hB = 0.f;
  } else {
    cA = sc[(size_t)s0 * 256 + hid];
    cB = sc[(size_t)(s0 + 1) * 256 + hid];
    hA = sh[(size_t)s0 * 256 + hid];
    hB = sh[(size_t)(s0 + 1) * 256 + hid];
  }
  if (ks == 0) {
    hbuf[0][0][hid] = hA;
    hbuf[0][1][hid] = hB;
  }
  const float* wbase = ws + WHH_OFF + ((size_t)ks * 128) * 1024 + (hid << 2);
  const float* xgA = ws + XGBUF_OFF + ((size_t)s0 * CH) * 1024 + (hid << 2);
  const float* xgB = xgA + (size_t)CH * 1024;
  float* foutA = ws + FSEL_OFF + (size_t)s0 * 256;
  float* foutB = foutA + 256;
  int koff = ks << 7;
  __syncthreads();

  int pp = 0;
  for (int tl = 0; tl < tend; tl++) {
    float4 xa = *(const float4*)(xgA + (size_t)tl * 1024);
    float4 xb = *(const float4*)(xgB + (size_t)tl * 1024);
    float iA, fA, gA, oA, iB, fB, gB, oB;
    if (ks == 0) {
      iA = xa.x; fA = xa.y; gA = xa.z; oA = xa.w;
      iB = xb.x; fB = xb.y; gB = xb.z; oB = xb.w;
    } else {
      iA = fA = gA = oA = iB = fB = gB = oB = 0.f;
    }
    const float* hAp = &hbuf[pp][0][koff];
    const float* hBp = &hbuf[pp][1][koff];
#pragma unroll 4
    for (int jb = 0; jb < 128; jb += 4) {
      float4 h4A = *(const float4*)(hAp + jb);
      float4 h4B = *(const float4*)(hBp + jb);
      float hAv[4] = {h4A.x, h4A.y, h4A.z, h4A.w};
      float hBv[4] = {h4B.x, h4B.y, h4B.z, h4B.w};
#pragma unroll
      for (int u = 0; u < 4; u++) {
        float4 wv = *(const float4*)(wbase + ((size_t)(jb + u) << 10));
        iA += wv.x * hAv[u]; fA += wv.y * hAv[u];
        gA += wv.z * hAv[u]; oA += wv.w * hAv[u];
        iB += wv.x * hBv[u]; fB += wv.y * hBv[u];
        gB += wv.z * hBv[u]; oB += wv.w * hBv[u];
      }
    }
    // pair-sum across ks halves (lane^1, same value on both lanes)
    iA += __shfl_xor(iA, 1, 64); fA += __shfl_xor(fA, 1, 64);
    gA += __shfl_xor(gA, 1, 64); oA += __shfl_xor(oA, 1, 64);
    iB += __shfl_xor(iB, 1, 64); fB += __shfl_xor(fB, 1, 64);
    gB += __shfl_xor(gB, 1, 64); oB += __shfl_xor(oB, 1, 64);

    cA = sigm(fA) * cA + sigm(iA) * tanhfast(gA);
    hA = sigm(oA) * tanhfast(cA);
    cB = sigm(fB) * cB + sigm(iB) * tanhfast(gB);
    hB = sigm(oB) * tanhfast(cB);
    if (ks == 0) {
      hbuf[pp ^ 1][0][hid] = hA;
      hbuf[pp ^ 1][1][hid] = hB;
      int t = t0c + tl;
      if (t == lenA - 1) foutA[hid] = hA;
      if (t == lenB - 1) foutB[hid] = hB;
    }
    __syncthreads();
    pp ^= 1;
  }
  if (ks == 0) {
    sh[(size_t)s0 * 256 + hid] = hA;
    sh[(size_t)(s0 + 1) * 256 + hid] = hB;
    sc[(size_t)s0 * 256 + hid] = cA;
    sc[(size_t)(s0 + 1) * 256 + hid] = cB;
  }
}

// fallback if ws too small for chunked xg: streams Wih+Whh per step (K=512)
__global__ __launch_bounds__(512, 2) void rec_fb_kernel(
    float* __restrict__ ws, const int* __restrict__ la,
    const int* __restrict__ lt, const int* __restrict__ ln) {
  __shared__ float hL[2][256];
  __shared__ float xL[2][256];
  int tid = threadIdx.x;
  int sl = tid >> 8;
  int hid = tid & 255;
  int seq = blockIdx.x * 2 + sl;
  int l = seq >> 5, b = seq & 31;
  int srcTr = (l == 1) ? 1 : ((l == 3) ? 2 : 0);
  const float* xrow = ws + M_OFF + (size_t)srcTr * MSZ + (size_t)b * TT * 128;
  const float* srow = ws + SUM_OFF + (size_t)l * MSZ + (size_t)b * TT * 128;
  const int* lens = (l == 1) ? lt : ((l == 3) ? ln : la);
  int b0 = b & ~1;
  int mylen = lens[b];
  int tmax = max(lens[b0], lens[b0 + 1]);
  const float* wh = ws + WHH_OFF + (hid << 2);
  const float* wi = ws + WIH_OFF + (hid << 2);
  float4 biasv = *(const float4*)&ws[BIAS_OFF + (hid << 2)];
  float c = 0.f;
  hL[sl][hid] = 0.f;
  xL[sl][hid] = hid < 128 ? xrow[hid] : xrow[hid - 128] - srow[hid - 128];
  __syncthreads();
  float* fout = ws + FSEL_OFF + (size_t)seq * 256;

  for (int t = 0; t < tmax; t++) {
    float gi = biasv.x, gf = biasv.y, gg = biasv.z, go = biasv.w;
    {
      const float* hp = &hL[sl][0];
#pragma unroll 4
      for (int k = 0; k < 256; k += 4) {
        float4 hv = *(const float4*)(hp + k);
        const float* w = wh + (size_t)k * 1024;
        float4 w0 = *(const float4*)(w);
        float4 w1 = *(const float4*)(w + 1024);
        float4 w2 = *(const float4*)(w + 2048);
        float4 w3 = *(const float4*)(w + 3072);
        gi += hv.x * w0.x + hv.y * w1.x + hv.z * w2.x + hv.w * w3.x;
        gf += hv.x * w0.y + hv.y * w1.y + hv.z * w2.y + hv.w * w3.y;
        gg += hv.x * w0.z + hv.y * w1.z + hv.z * w2.z + hv.w * w3.z;
        go += hv.x * w0.w + hv.y * w1.w + hv.z * w2.w + hv.w * w3.w;
      }
    }
    {
      const float* xp = &xL[sl][0];
#pragma unroll 4
      for (int k = 0; k < 256; k += 4) {
        float4 xv = *(const float4*)(xp + k);
        const float* w = wi + (size_t)k * 1024;
        float4 w0 = *(const float4*)(w);
        float4 w1 = *(const float4*)(w + 1024);
        float4 w2 = *(const float4*)(w + 2048);
        float4 w3 = *(const float4*)(w + 3072);
        gi += xv.x * w0.x + xv.y * w1.x + xv.z * w2.x + xv.w * w3.x;
        gf += xv.x * w0.y + xv.y * w1.y + xv.z * w2.y + xv.w * w3.y;
        gg += xv.x * w0.z + xv.y * w1.z + xv.z * w2.z + xv.w * w3.z;
        go += xv.x * w0.w + xv.y * w1.w + xv.z * w2.w + xv.w * w3.w;
      }
    }
    float c_new = sigm(gf) * c + sigm(gi) * tanhfast(gg);
    c = c_new;
    float h = sigm(go) * tanhfast(c_new);
    __syncthreads();
    hL[sl][hid] = h;
    if (t + 1 < TT) {
      int tn = t + 1;
      xL[sl][hid] = hid < 128 ? xrow[tn * 128 + hid]
                              : xrow[tn * 128 + hid - 128] - srow[tn * 128 + hid - 128];
    }
    if (t == mylen - 1) fout[hid] = h;
    __syncthreads();
  }
}

__global__ __launch_bounds__(256) void finish_kernel(
    const float* __restrict__ ws, const float* __restrict__ W1,
    const float* __restrict__ b1, const float* __restrict__ W2,
    const float* __restrict__ b2, const float* __restrict__ W3,
    const float* __restrict__ b3, float* __restrict__ out) {
  __shared__ float oL[256];
  __shared__ float wsum[4];
  int tid = threadIdx.x;
  int p = blockIdx.x >> 5, b = blockIdx.x & 31;
  const float* fa = ws + FSEL_OFF + (size_t)((2 * p) * 32 + b) * 256;
  const float* fb = ws + FSEL_OFF + (size_t)((2 * p + 1) * 32 + b) * 256;
  oL[tid] = fa[tid];
  __syncthreads();
  float a1 = b1[tid], a2 = b2[tid], a3 = b3[tid];
  const float* w1r = W1 + tid * 256;
  const float* w2r = W2 + tid * 256;
  const float* w3r = W3 + tid * 256;
  for (int k = 0; k < 256; k++) {
    float ov = oL[k];
    a1 += ov * w1r[k];
    a2 += ov * w2r[k];
    a3 += ov * w3r[k];
  }
  float cg = sigm(a1) * leaky(a2);
  float res = oL[tid] + sigm(a3) * leaky(cg);
  float d = res - fb[tid] + 1e-6f;
  float sq = d * d;
  for (int m = 32; m >= 1; m >>= 1) sq += __shfl_down(sq, m, 64);
  if ((tid & 63) == 0) wsum[tid >> 6] = sq;
  __syncthreads();
  if (tid == 0) {
    float s = wsum[0] + wsum[1] + wsum[2] + wsum[3];
    out[p * BB + b] = expf(sqrtf(s));
  }
}

extern "C" void kernel_launch(void* const* d_in, const int* in_sizes, int n_in,
                              void* d_out, int out_size, void* d_ws, size_t ws_size,
                              hipStream_t stream) {
  const float* anchor = (const float*)d_in[0];
  const float* trajs = (const float*)d_in[1];
  const float* negat = (const float*)d_in[2];
  const int* la = (const int*)d_in[3];
  const int* lt = (const int*)d_in[4];
  const int* ln = (const int*)d_in[5];
  const float* Wm = (const float*)d_in[6];
  const float* bm = (const float*)d_in[7];
  const float* Wih = (const float*)d_in[8];
  const float* Whh = (const float*)d_in[9];
  const float* bih = (const float*)d_in[10];
  const float* bhh = (const float*)d_in[11];
  const float* W1 = (const float*)d_in[12];
  const float* b1 = (const float*)d_in[13];
  const float* W2 = (const float*)d_in[14];
  const float* b2 = (const float*)d_in[15];
  const float* W3 = (const float*)d_in[16];
  const float* b3 = (const float*)d_in[17];
  float* ws = (float*)d_ws;
  float* out = (float*)d_out;

  embed_kernel<<<(3 * BB * TT * 128) / 256, 256, 0, stream>>>(anchor, trajs, negat, Wm, bm, ws);
  mask_kernel<<<(3 * BB * TT) / 256, 256, 0, stream>>>(anchor, trajs, negat, ws);
  wt_kernel<<<2052, 256, 0, stream>>>(Wih, Whh, bih, bhh, ws);
  attn_kernel<<<4096, 256, 0, stream>>>(ws);

  // pick the largest xg chunk that fits the workspace
  size_t basebytes = XGBUF_OFF * sizeof(float);
  int CH = 0;
  const int cands[4] = {512, 256, 128, 64};
  for (int i = 0; i < 4; i++) {
    size_t need = basebytes + (size_t)cands[i] * 128 * 1024 * sizeof(float);
    if (need <= ws_size) { CH = cands[i]; break; }
  }
  if (CH) {
    int nch = TT / CH;
    int xgrid = 128 * ((CH >> 6) << 2);
    for (int c = 0; c < nch; c++) {
      int tc0 = c * CH;
      xg_kernel<<<xgrid, 256, 0, stream>>>(ws, tc0, CH, la, lt, ln);
      rec2_kernel<<<64, 512, 0, stream>>>(ws, la, lt, ln, tc0, CH);
    }
  } else {
    rec_fb_kernel<<<64, 512, 0, stream>>>(ws, la, lt, ln);
  }
  finish_kernel<<<64, 256, 0, stream>>>(ws, W1, b1, W2, b2, W3, b3, out);
}